// Round 11
// baseline (65.390 us; speedup 1.0000x reference)
//
#include <hip/hip_runtime.h>

// out[N,32] = scatter_add over edges e: values[e] * x[cols[e], :] into row rows[e]
//
// Pipeline (superbucket = row >> 7, 128 rows, nb128 = ceil(N/128) = 782):
//   k1 bin_sorted : one WG per 4096-edge chunk. LDS counting sort by superbucket,
//                   CONTIGUOUS write of the sorted chunk (write-amp 1.0) +
//                   per-(chunk,bucket) ushort segment starts into desc.
//   k2 spmm_sb2   : ONE 1024-thread block per superbucket. Streams the
//                   superbucket's edges once via segment walk with 8-lane-LEADER
//                   binary search (leaders search, others shuffle+walk), LDS
//                   counting-sorts the whole run (MAXB=4096 -> single pass) by
//                   the 7-bit row-local index, then each of 128 8-lane groups
//                   owns ONE row and accumulates in registers. No float atomics.
//
// indices: d_in[0] = int[2*NNZ], values: d_in[1] = float[NNZ], x: d_in[2] = float[N*32]

#define D 32
#define SBSHIFT 7
#define NB128_MAX 1024
#define CHUNK 4096              // edges per bin chunk (sorted unit)
#define EPT (CHUNK / 256)       // 16 edges per thread in bin
#define NCH_MAX 512             // max chunks (nnz <= 2.1M)
#define MAXB 4096               // sort-batch size in spmm (4 slots/thread)

typedef unsigned long long ull;

// ---------- k1: per-chunk counting sort by superbucket ----------
__global__ __launch_bounds__(256) void bin_sorted_kernel(
    const int* __restrict__ idx, const float* __restrict__ vals,
    ull* __restrict__ packed, unsigned short* __restrict__ desc,
    int nnz, int nb)
{
    __shared__ int cnt[NB128_MAX];       // counters, then cursors
    __shared__ int off[NB128_MAX + 1];   // exclusive scan
    __shared__ int sm[256];

    int chunk = blockIdx.x;
    int base = chunk * CHUNK;
    int m = min(CHUNK, nnz - base);

    for (int i = threadIdx.x; i < nb; i += 256) cnt[i] = 0;
    __syncthreads();

    // load edges into registers, histogram superbuckets
    ull pv[EPT];
    int pb[EPT];
    #pragma unroll
    for (int j = 0; j < EPT; ++j) {
        int i = threadIdx.x + j * 256;
        pb[j] = -1;
        if (i < m) {
            int e = base + i;
            int r = idx[e];
            unsigned c = (unsigned)idx[nnz + e];
            unsigned vb = __float_as_uint(vals[e]);
            pv[j] = ((ull)vb << 32) | ((ull)c << SBSHIFT) | (unsigned)(r & 127);
            pb[j] = r >> SBSHIFT;
            atomicAdd(&cnt[pb[j]], 1);
        }
    }
    __syncthreads();

    // exclusive scan of cnt[0..nb) -> off[0..nb], 4 elems/thread (nb <= 1024)
    {
        int b4 = threadIdx.x * 4;
        int v0 = (b4 + 0 < nb) ? cnt[b4 + 0] : 0;
        int v1 = (b4 + 1 < nb) ? cnt[b4 + 1] : 0;
        int v2 = (b4 + 2 < nb) ? cnt[b4 + 2] : 0;
        int v3 = (b4 + 3 < nb) ? cnt[b4 + 3] : 0;
        int tot = v0 + v1 + v2 + v3;
        sm[threadIdx.x] = tot;
        __syncthreads();
        for (int o = 1; o < 256; o <<= 1) {
            int t = sm[threadIdx.x];
            int u = (threadIdx.x >= o) ? sm[threadIdx.x - o] : 0;
            __syncthreads();
            sm[threadIdx.x] = t + u;
            __syncthreads();
        }
        int ex = sm[threadIdx.x] - tot;
        if (b4 + 0 < nb) off[b4 + 0] = ex;
        if (b4 + 1 < nb) off[b4 + 1] = ex + v0;
        if (b4 + 2 < nb) off[b4 + 2] = ex + v0 + v1;
        if (b4 + 3 < nb) off[b4 + 3] = ex + v0 + v1 + v2;
        if (threadIdx.x == 0) off[nb] = m;
    }
    __syncthreads();

    // cursors
    for (int i = threadIdx.x; i < nb; i += 256) cnt[i] = off[i];
    __syncthreads();

    // scatter into the chunk's own contiguous window (full-line coverage)
    #pragma unroll
    for (int j = 0; j < EPT; ++j) {
        if (pb[j] >= 0) {
            int pos = atomicAdd(&cnt[pb[j]], 1);
            packed[(size_t)base + pos] = pv[j];
        }
    }

    // segment starts for this chunk (coalesced ushort writes)
    for (int i = threadIdx.x; i <= nb; i += 256)
        desc[(size_t)chunk * (nb + 1) + i] = (unsigned short)off[i];
}

// ---------- k2: whole-superbucket counting-sort + register accumulate ----------
__global__ __launch_bounds__(1024, 8) void spmm_sb2_kernel(
    const unsigned short* __restrict__ desc,
    const ull* __restrict__ packed,
    const float* __restrict__ x, float* __restrict__ out,
    int N, int nb, int nchunk)
{
    __shared__ ull sp[MAXB];
    __shared__ int cnt[128];
    __shared__ int off[128];
    __shared__ int cur[128];
    __shared__ int segScan[NCH_MAX + 1];
    __shared__ unsigned short segStart[NCH_MAX];
    __shared__ int sm2[NCH_MAX];

    int j = blockIdx.x;            // superbucket
    int t = threadIdx.x;
    int lane = t & 63;
    int g = t >> 3;                // owned row-local index (128 groups)
    int q = t & 7;                 // 4 columns each
    const float4* __restrict__ x4 = reinterpret_cast<const float4*>(x);

    // ---- Phase A: segment table, 1 chunk-slot per thread ----
    int len = 0;
    if (t < nchunk) {
        int a  = desc[(size_t)t * (nb + 1) + j];
        int bd = desc[(size_t)t * (nb + 1) + j + 1];
        segStart[t] = (unsigned short)a;
        len = bd - a;
    } else if (t < NCH_MAX) {
        segStart[t] = 0;
    }
    if (t < NCH_MAX) sm2[t] = len;
    __syncthreads();
    for (int o = 1; o < NCH_MAX; o <<= 1) {
        int v = 0;
        if (t < NCH_MAX) { v = sm2[t]; if (t >= o) v += sm2[t - o]; }
        __syncthreads();
        if (t < NCH_MAX) sm2[t] = v;
        __syncthreads();
    }
    if (t < NCH_MAX) segScan[t] = sm2[t] - len;       // exclusive
    if (t == NCH_MAX - 1) segScan[NCH_MAX] = sm2[t];  // total
    __syncthreads();
    int total = segScan[NCH_MAX];

    float4 acc = make_float4(0.f, 0.f, 0.f, 0.f);

    // ---- Phase B: batched sort + accumulate (typically ONE pass: mean run 2046) ----
    for (int bb = 0; bb < total; bb += MAXB) {
        int m = min(MAXB, total - bb);

        if (t < 128) cnt[t] = 0;
        __syncthreads();

        ull pv[MAXB / 1024];
        bool have[MAXB / 1024];
        #pragma unroll
        for (int jj = 0; jj < MAXB / 1024; ++jj) {
            int i = t + jj * 1024;
            have[jj] = (i < m);
            int gi = bb + (have[jj] ? i : (m - 1));   // clamp inactive lanes
            // 8-lane-leader binary search; others shuffle + short walk
            int cl = 0;
            if ((lane & 7) == 0) {
                int lgi = gi;                          // leader's own gi
                #pragma unroll
                for (int st = NCH_MAX / 2; st >= 1; st >>= 1) {
                    int nc = cl + st;
                    if (nc <= NCH_MAX - 1 && segScan[nc] <= lgi) cl = nc;
                }
            }
            cl = __shfl(cl, lane & ~7, 64);
            while (cl < NCH_MAX - 1 && segScan[cl + 1] <= gi) ++cl;
            if (have[jj]) {
                ull p = packed[(size_t)cl * CHUNK + (int)segStart[cl] + (gi - segScan[cl])];
                pv[jj] = p;
                atomicAdd(&cnt[(int)(p & 127)], 1);
            }
        }
        __syncthreads();

        // exclusive scan of 128 counters: single wave, 2 per lane, shuffle scan
        if (t < 64) {
            int a  = cnt[2 * t];
            int b2 = cnt[2 * t + 1];
            int s2 = a + b2;
            int ssum = s2;
            #pragma unroll
            for (int d2 = 1; d2 < 64; d2 <<= 1) {
                int u = __shfl_up(ssum, d2, 64);
                if (t >= d2) ssum += u;
            }
            int ex = ssum - s2;
            off[2 * t] = ex;          cur[2 * t] = ex;
            off[2 * t + 1] = ex + a;  cur[2 * t + 1] = ex + a;
        }
        __syncthreads();

        // scatter into row-sorted order
        #pragma unroll
        for (int jj = 0; jj < MAXB / 1024; ++jj) {
            if (have[jj]) {
                int rl = (int)(pv[jj] & 127);
                int pos = atomicAdd(&cur[rl], 1);
                sp[pos] = pv[jj];
            }
        }
        __syncthreads();

        // group g accumulates its own row's segment — registers, no atomics
        int rs = off[g];
        int re = rs + cnt[g];
        int k = rs;
        for (; k + 3 < re; k += 4) {       // 4 gathers in flight
            ull p0 = sp[k], p1 = sp[k + 1], p2 = sp[k + 2], p3 = sp[k + 3];
            int c0 = (int)((p0 >> SBSHIFT) & 0x1ffff);
            int c1 = (int)((p1 >> SBSHIFT) & 0x1ffff);
            int c2 = (int)((p2 >> SBSHIFT) & 0x1ffff);
            int c3 = (int)((p3 >> SBSHIFT) & 0x1ffff);
            float v0 = __uint_as_float((unsigned)(p0 >> 32));
            float v1 = __uint_as_float((unsigned)(p1 >> 32));
            float v2 = __uint_as_float((unsigned)(p2 >> 32));
            float v3 = __uint_as_float((unsigned)(p3 >> 32));
            float4 a0 = x4[(size_t)c0 * (D / 4) + q];
            float4 a1 = x4[(size_t)c1 * (D / 4) + q];
            float4 a2 = x4[(size_t)c2 * (D / 4) + q];
            float4 a3 = x4[(size_t)c3 * (D / 4) + q];
            acc.x += v0 * a0.x; acc.y += v0 * a0.y; acc.z += v0 * a0.z; acc.w += v0 * a0.w;
            acc.x += v1 * a1.x; acc.y += v1 * a1.y; acc.z += v1 * a1.z; acc.w += v1 * a1.w;
            acc.x += v2 * a2.x; acc.y += v2 * a2.y; acc.z += v2 * a2.z; acc.w += v2 * a2.w;
            acc.x += v3 * a3.x; acc.y += v3 * a3.y; acc.z += v3 * a3.z; acc.w += v3 * a3.w;
        }
        for (; k < re; ++k) {
            ull p = sp[k];
            int c = (int)((p >> SBSHIFT) & 0x1ffff);
            float v = __uint_as_float((unsigned)(p >> 32));
            float4 a = x4[(size_t)c * (D / 4) + q];
            acc.x += v * a.x; acc.y += v * a.y; acc.z += v * a.z; acc.w += v * a.w;
        }
        __syncthreads();   // protect sp/cnt before next batch
    }

    int row = (j << SBSHIFT) + g;
    if (row < N)
        reinterpret_cast<float4*>(out)[(size_t)row * (D / 4) + q] = acc;
}

// ---------- fallback: direct atomic scatter (round-1) ----------
__global__ __launch_bounds__(256) void spmm_scatter_kernel(
    const int* __restrict__ idx, const float* __restrict__ vals,
    const float* __restrict__ x, float* __restrict__ out, int nnz)
{
    int t = blockIdx.x * blockDim.x + threadIdx.x;
    int e = t >> 3;
    int q = t & 7;
    if (e >= nnz) return;
    int r = idx[e];
    int c = idx[nnz + e];
    float v = vals[e];
    const float4 xv = reinterpret_cast<const float4*>(x)[(size_t)c * (D / 4) + q];
    float* o = out + (size_t)r * D + q * 4;
    atomicAdd(o + 0, v * xv.x);
    atomicAdd(o + 1, v * xv.y);
    atomicAdd(o + 2, v * xv.z);
    atomicAdd(o + 3, v * xv.w);
}

static inline size_t align256(size_t v) { return (v + 255) & ~(size_t)255; }

extern "C" void kernel_launch(void* const* d_in, const int* in_sizes, int n_in,
                              void* d_out, int out_size, void* d_ws, size_t ws_size,
                              hipStream_t stream)
{
    const int* idx   = (const int*)d_in[0];
    const float* val = (const float*)d_in[1];
    const float* x   = (const float*)d_in[2];
    float* out       = (float*)d_out;

    const int nnz   = in_sizes[1];
    const int N     = out_size / D;
    const int nb128 = (N + 127) >> SBSHIFT;   // superbuckets
    const int nchunk = (nnz + CHUNK - 1) / CHUNK;

    size_t off_packed = 0;
    size_t off_desc   = align256(off_packed + (size_t)nnz * 8);
    size_t ws_needed  = off_desc + (size_t)nchunk * (nb128 + 1) * 2;

    // col 17 bits; nb128 within scan width; nchunk within segment table
    if (ws_size < ws_needed || nb128 > NB128_MAX || nchunk > NCH_MAX || N > 131072) {
        hipMemsetAsync(d_out, 0, (size_t)out_size * sizeof(float), stream);
        const long long total = (long long)nnz * 8;
        spmm_scatter_kernel<<<(int)((total + 255) / 256), 256, 0, stream>>>(
            idx, val, x, out, nnz);
        return;
    }

    char* ws = (char*)d_ws;
    ull* packed = (ull*)(ws + off_packed);
    unsigned short* desc = (unsigned short*)(ws + off_desc);

    bin_sorted_kernel<<<nchunk, 256, 0, stream>>>(idx, val, packed, desc, nnz, nb128);
    spmm_sb2_kernel<<<nb128, 1024, 0, stream>>>(desc, packed, x, out, N, nb128, nchunk);
}

// Round 12
// 63.381 us; speedup vs baseline: 1.0317x; 1.0317x over previous
//
#include <hip/hip_runtime.h>

// out[N,32] = scatter_add over edges e: values[e] * x[cols[e], :] into row rows[e]
//
// Pipeline (superbucket = row >> 7, 128 rows, nb128 = ceil(N/128) = 782):
//   k1 bin_sorted : one WG per 4096-edge chunk. LDS counting sort by superbucket
//                   (counters+scan in LDS, edges in registers), then CONTIGUOUS
//                   write of the sorted chunk into packed[chunk*4096..] (write-amp
//                   1.0) + per-(chunk,bucket) ushort segment starts into desc.
//   k2 spmm_sb    : ONE 1024-thread block per superbucket (grid=782, 16 waves).
//                   Streams the superbucket's edges exactly once via
//                   binary-search segment walk, LDS counting-sorts each
//                   2048-edge batch by the 7-bit row-local index, then each of
//                   128 8-lane groups owns ONE row and accumulates in
//                   registers. No float atomics anywhere.
//
// Measured (round 10): total 64.3 us; spmm 47 us @ FETCH 100 MB (~2.1-2.5 TB/s
// L2-miss path = random-gather floor, confirmed by R11 A/B), bin ~15 us.
//
// indices: d_in[0] = int[2*NNZ], values: d_in[1] = float[NNZ], x: d_in[2] = float[N*32]

#define D 32
#define SBSHIFT 7
#define NB128_MAX 1024
#define CHUNK 4096              // edges per bin chunk (sorted unit)
#define EPT (CHUNK / 256)       // 16 edges per thread in bin
#define NCH_MAX 512             // max chunks (nnz <= 2.1M)
#define MAXB 2048               // sort-batch size in spmm (2 slots/thread)

typedef unsigned long long ull;

// ---------- k1: per-chunk counting sort by superbucket ----------
__global__ __launch_bounds__(256) void bin_sorted_kernel(
    const int* __restrict__ idx, const float* __restrict__ vals,
    ull* __restrict__ packed, unsigned short* __restrict__ desc,
    int nnz, int nb)
{
    __shared__ int cnt[NB128_MAX];       // counters, then cursors
    __shared__ int off[NB128_MAX + 1];   // exclusive scan
    __shared__ int sm[256];

    int chunk = blockIdx.x;
    int base = chunk * CHUNK;
    int m = min(CHUNK, nnz - base);

    for (int i = threadIdx.x; i < nb; i += 256) cnt[i] = 0;
    __syncthreads();

    // load edges into registers, histogram superbuckets
    ull pv[EPT];
    int pb[EPT];
    #pragma unroll
    for (int j = 0; j < EPT; ++j) {
        int i = threadIdx.x + j * 256;
        pb[j] = -1;
        if (i < m) {
            int e = base + i;
            int r = idx[e];
            unsigned c = (unsigned)idx[nnz + e];
            unsigned vb = __float_as_uint(vals[e]);
            pv[j] = ((ull)vb << 32) | ((ull)c << SBSHIFT) | (unsigned)(r & 127);
            pb[j] = r >> SBSHIFT;
            atomicAdd(&cnt[pb[j]], 1);
        }
    }
    __syncthreads();

    // exclusive scan of cnt[0..nb) -> off[0..nb], 4 elems/thread (nb <= 1024)
    {
        int b4 = threadIdx.x * 4;
        int v0 = (b4 + 0 < nb) ? cnt[b4 + 0] : 0;
        int v1 = (b4 + 1 < nb) ? cnt[b4 + 1] : 0;
        int v2 = (b4 + 2 < nb) ? cnt[b4 + 2] : 0;
        int v3 = (b4 + 3 < nb) ? cnt[b4 + 3] : 0;
        int tot = v0 + v1 + v2 + v3;
        sm[threadIdx.x] = tot;
        __syncthreads();
        for (int o = 1; o < 256; o <<= 1) {
            int t = sm[threadIdx.x];
            int u = (threadIdx.x >= o) ? sm[threadIdx.x - o] : 0;
            __syncthreads();
            sm[threadIdx.x] = t + u;
            __syncthreads();
        }
        int ex = sm[threadIdx.x] - tot;
        if (b4 + 0 < nb) off[b4 + 0] = ex;
        if (b4 + 1 < nb) off[b4 + 1] = ex + v0;
        if (b4 + 2 < nb) off[b4 + 2] = ex + v0 + v1;
        if (b4 + 3 < nb) off[b4 + 3] = ex + v0 + v1 + v2;
        if (threadIdx.x == 0) off[nb] = m;
    }
    __syncthreads();

    // cursors
    for (int i = threadIdx.x; i < nb; i += 256) cnt[i] = off[i];
    __syncthreads();

    // scatter into the chunk's own contiguous window (full-line coverage)
    #pragma unroll
    for (int j = 0; j < EPT; ++j) {
        if (pb[j] >= 0) {
            int pos = atomicAdd(&cnt[pb[j]], 1);
            packed[(size_t)base + pos] = pv[j];
        }
    }

    // segment starts for this chunk (coalesced ushort writes)
    for (int i = threadIdx.x; i <= nb; i += 256)
        desc[(size_t)chunk * (nb + 1) + i] = (unsigned short)off[i];
}

// ---------- k2: whole-superbucket counting-sort + register accumulate ----------
__global__ __launch_bounds__(1024, 8) void spmm_sb_kernel(
    const unsigned short* __restrict__ desc,
    const ull* __restrict__ packed,
    const float* __restrict__ x, float* __restrict__ out,
    int N, int nb, int nchunk)
{
    __shared__ ull sp[MAXB];
    __shared__ int cnt[128];
    __shared__ int off[128];
    __shared__ int cur[128];
    __shared__ int segScan[NCH_MAX + 1];
    __shared__ unsigned short segStart[NCH_MAX];
    __shared__ int sm2[NCH_MAX];

    int j = blockIdx.x;            // superbucket
    int t = threadIdx.x;
    int g = t >> 3;                // owned row-local index (128 groups)
    int q = t & 7;                 // 4 columns each
    const float4* __restrict__ x4 = reinterpret_cast<const float4*>(x);

    // ---- Phase A: segment table, 1 chunk-slot per thread ----
    int len = 0;
    if (t < nchunk) {
        int a  = desc[(size_t)t * (nb + 1) + j];
        int bd = desc[(size_t)t * (nb + 1) + j + 1];
        segStart[t] = (unsigned short)a;
        len = bd - a;
    } else if (t < NCH_MAX) {
        segStart[t] = 0;
    }
    if (t < NCH_MAX) sm2[t] = len;
    __syncthreads();
    for (int o = 1; o < NCH_MAX; o <<= 1) {
        int v = 0;
        if (t < NCH_MAX) { v = sm2[t]; if (t >= o) v += sm2[t - o]; }
        __syncthreads();
        if (t < NCH_MAX) sm2[t] = v;
        __syncthreads();
    }
    if (t < NCH_MAX) segScan[t] = sm2[t] - len;       // exclusive
    if (t == NCH_MAX - 1) segScan[NCH_MAX] = sm2[t];  // total
    __syncthreads();
    int total = segScan[NCH_MAX];

    float4 acc = make_float4(0.f, 0.f, 0.f, 0.f);

    // ---- Phase B: batched sort + accumulate (no filter — every edge is ours) ----
    for (int bb = 0; bb < total; bb += MAXB) {
        int m = min(MAXB, total - bb);

        if (t < 128) cnt[t] = 0;
        __syncthreads();

        ull pv[MAXB / 1024];
        bool have[MAXB / 1024];
        #pragma unroll
        for (int jj = 0; jj < MAXB / 1024; ++jj) {
            int i = t + jj * 1024;
            have[jj] = (i < m);
            if (have[jj]) {
                int gi = bb + i;
                // binary search: max c with segScan[c] <= gi
                int c = 0;
                #pragma unroll
                for (int st = NCH_MAX / 2; st >= 1; st >>= 1) {
                    int nc = c + st;
                    if (nc <= NCH_MAX - 1 && segScan[nc] <= gi) c = nc;
                }
                ull p = packed[(size_t)c * CHUNK + (int)segStart[c] + (gi - segScan[c])];
                pv[jj] = p;
                atomicAdd(&cnt[(int)(p & 127)], 1);
            }
        }
        __syncthreads();

        // exclusive scan of 128 counters (threads 0..127, Hillis-Steele in LDS)
        if (t < 128) sm2[t] = cnt[t];
        __syncthreads();
        for (int o = 1; o < 128; o <<= 1) {
            int v = 0;
            if (t < 128) { v = sm2[t]; if (t >= o) v += sm2[t - o]; }
            __syncthreads();
            if (t < 128) sm2[t] = v;
            __syncthreads();
        }
        if (t < 128) {
            int ex = sm2[t] - cnt[t];
            off[t] = ex;
            cur[t] = ex;
        }
        __syncthreads();

        // scatter into row-sorted order
        #pragma unroll
        for (int jj = 0; jj < MAXB / 1024; ++jj) {
            if (have[jj]) {
                int rl = (int)(pv[jj] & 127);
                int pos = atomicAdd(&cur[rl], 1);
                sp[pos] = pv[jj];
            }
        }
        __syncthreads();

        // group g accumulates its own row's segment — registers, no atomics
        int rs = off[g];
        int re = rs + cnt[g];
        int k = rs;
        for (; k + 3 < re; k += 4) {       // 4 gathers in flight
            ull p0 = sp[k], p1 = sp[k + 1], p2 = sp[k + 2], p3 = sp[k + 3];
            int c0 = (int)((p0 >> SBSHIFT) & 0x1ffff);
            int c1 = (int)((p1 >> SBSHIFT) & 0x1ffff);
            int c2 = (int)((p2 >> SBSHIFT) & 0x1ffff);
            int c3 = (int)((p3 >> SBSHIFT) & 0x1ffff);
            float v0 = __uint_as_float((unsigned)(p0 >> 32));
            float v1 = __uint_as_float((unsigned)(p1 >> 32));
            float v2 = __uint_as_float((unsigned)(p2 >> 32));
            float v3 = __uint_as_float((unsigned)(p3 >> 32));
            float4 a0 = x4[(size_t)c0 * (D / 4) + q];
            float4 a1 = x4[(size_t)c1 * (D / 4) + q];
            float4 a2 = x4[(size_t)c2 * (D / 4) + q];
            float4 a3 = x4[(size_t)c3 * (D / 4) + q];
            acc.x += v0 * a0.x; acc.y += v0 * a0.y; acc.z += v0 * a0.z; acc.w += v0 * a0.w;
            acc.x += v1 * a1.x; acc.y += v1 * a1.y; acc.z += v1 * a1.z; acc.w += v1 * a1.w;
            acc.x += v2 * a2.x; acc.y += v2 * a2.y; acc.z += v2 * a2.z; acc.w += v2 * a2.w;
            acc.x += v3 * a3.x; acc.y += v3 * a3.y; acc.z += v3 * a3.z; acc.w += v3 * a3.w;
        }
        for (; k < re; ++k) {
            ull p = sp[k];
            int c = (int)((p >> SBSHIFT) & 0x1ffff);
            float v = __uint_as_float((unsigned)(p >> 32));
            float4 a = x4[(size_t)c * (D / 4) + q];
            acc.x += v * a.x; acc.y += v * a.y; acc.z += v * a.z; acc.w += v * a.w;
        }
        __syncthreads();   // protect sp/cnt before next batch
    }

    int row = (j << SBSHIFT) + g;
    if (row < N)
        reinterpret_cast<float4*>(out)[(size_t)row * (D / 4) + q] = acc;
}

// ---------- fallback: direct atomic scatter (round-1) ----------
__global__ __launch_bounds__(256) void spmm_scatter_kernel(
    const int* __restrict__ idx, const float* __restrict__ vals,
    const float* __restrict__ x, float* __restrict__ out, int nnz)
{
    int t = blockIdx.x * blockDim.x + threadIdx.x;
    int e = t >> 3;
    int q = t & 7;
    if (e >= nnz) return;
    int r = idx[e];
    int c = idx[nnz + e];
    float v = vals[e];
    const float4 xv = reinterpret_cast<const float4*>(x)[(size_t)c * (D / 4) + q];
    float* o = out + (size_t)r * D + q * 4;
    atomicAdd(o + 0, v * xv.x);
    atomicAdd(o + 1, v * xv.y);
    atomicAdd(o + 2, v * xv.z);
    atomicAdd(o + 3, v * xv.w);
}

static inline size_t align256(size_t v) { return (v + 255) & ~(size_t)255; }

extern "C" void kernel_launch(void* const* d_in, const int* in_sizes, int n_in,
                              void* d_out, int out_size, void* d_ws, size_t ws_size,
                              hipStream_t stream)
{
    const int* idx   = (const int*)d_in[0];
    const float* val = (const float*)d_in[1];
    const float* x   = (const float*)d_in[2];
    float* out       = (float*)d_out;

    const int nnz   = in_sizes[1];
    const int N     = out_size / D;
    const int nb128 = (N + 127) >> SBSHIFT;   // superbuckets
    const int nchunk = (nnz + CHUNK - 1) / CHUNK;

    size_t off_packed = 0;
    size_t off_desc   = align256(off_packed + (size_t)nnz * 8);
    size_t ws_needed  = off_desc + (size_t)nchunk * (nb128 + 1) * 2;

    // col 17 bits; nb128 within scan width; nchunk within segment table
    if (ws_size < ws_needed || nb128 > NB128_MAX || nchunk > NCH_MAX || N > 131072) {
        hipMemsetAsync(d_out, 0, (size_t)out_size * sizeof(float), stream);
        const long long total = (long long)nnz * 8;
        spmm_scatter_kernel<<<(int)((total + 255) / 256), 256, 0, stream>>>(
            idx, val, x, out, nnz);
        return;
    }

    char* ws = (char*)d_ws;
    ull* packed = (ull*)(ws + off_packed);
    unsigned short* desc = (unsigned short*)(ws + off_desc);

    bin_sorted_kernel<<<nchunk, 256, 0, stream>>>(idx, val, packed, desc, nnz, nb128);
    spmm_sb_kernel<<<nb128, 1024, 0, stream>>>(desc, packed, x, out, N, nb128, nchunk);
}